// Round 1
// 182.927 us; speedup vs baseline: 1.0941x; 1.0941x over previous
//
#include <hip/hip_runtime.h>
#include <math.h>

// ---------------------------------------------------------------------------
// Fused 11-layer funnel MLP, round 4.
// Round-3 analysis: no pipe saturated (MFMA 16%, VALU 28%, LDS ~30%, HBM 2%)
// => latency-bound at 8 waves/CU (2/SIMD). Arena was 8KB/wave (32 rows).
// Round 4: 16 rows/wave (single B-fragment), arena 4KB/wave, 1024-thread
// blocks with 16 waves => 16 waves/CU (4/SIMD) at the SAME 153.6KB LDS.
// Doubles TLP to hide the serial layer-chain + tail latency; per-wave ILP
// halves but big layers keep NMT=6..8 independent accumulator chains.
// All round-2/3 machinery retained: fragment-major conflict-free LDS,
// bias folded into MFMA pad columns, 1.0-generator pad rows, packed
// v_cvt_pk_bf16_f32 epilogue, tail weights preloaded to VGPRs, x prefetch.
// ---------------------------------------------------------------------------

using bf16x8 = __attribute__((ext_vector_type(8))) short;   // 8 bf16 = 4 VGPRs
using f32x4  = __attribute__((ext_vector_type(4))) float;
using u16x8  = __attribute__((ext_vector_type(8))) unsigned short;
using u32x2  = __attribute__((ext_vector_type(2))) unsigned;
typedef __bf16 bf16x2_t __attribute__((ext_vector_type(2)));

namespace {
constexpr int NL = 11;
constexpr int IN_[NL]   = {15, 30, 60, 90, 120, 90, 60, 30, 15, 10, 5};
constexpr int OUT_[NL]  = {30, 60, 90, 120, 90, 60, 30, 15, 10, 5, 1};
constexpr int KP_[NL]   = {32, 32, 64, 96, 128, 96, 64, 32, 32, 32, 32};  // in, pad 32
constexpr int NP_[NL]   = {32, 64, 96, 128, 96, 64, 32, 16, 16, 16, 16};  // out, pad 16
constexpr int WOFF_[NL] = {0, 1024, 3072, 9216, 21504, 33792, 39936, 41984, 42496, 43008, 43520};
constexpr int WTOT      = 44032;   // shorts
constexpr int ACT_OFF   = WTOT;
constexpr int WAVES     = 16;
constexpr int THREADS   = WAVES * 64;                 // 1024
constexpr int ROWS_PER_WAVE  = 16;
constexpr int ROWS_PER_BLOCK = WAVES * ROWS_PER_WAVE; // 256 (unchanged)
constexpr int ARENA     = 2048;    // shorts per wave (4 KB)
constexpr int LDS_BYTES = (WTOT + WAVES * ARENA) * 2; // 153600
}

// fp32 -> bf16 RNE (scalar, staging only)
__device__ __forceinline__ unsigned short f2bf(float f) {
    unsigned u = __float_as_uint(f);
    u += 0x7fffu + ((u >> 16) & 1u);
    return (unsigned short)(u >> 16);
}

// packed fp32x2 -> bf16x2 (RNE); gfx950 has v_cvt_pk_bf16_f32
__device__ __forceinline__ unsigned pk2(float a, float b) {
#if __has_builtin(__builtin_amdgcn_cvt_pk_bf16_f32)
    return __builtin_bit_cast(unsigned, __builtin_amdgcn_cvt_pk_bf16_f32(a, b));
#else
    bf16x2_t c;
    c[0] = (__bf16)a;
    c[1] = (__bf16)b;
    return __builtin_bit_cast(unsigned, c);
#endif
}

// Stage layer L's weights (A-frag-major) with bias/one-hot pads folded in.
template <int L>
__device__ __forceinline__ void stage_w(const float* __restrict__ W,
                                        const float* __restrict__ B,
                                        short* wlds, int tid) {
    constexpr int KP = KP_[L], NP = NP_[L], INl = IN_[L], OUTl = OUT_[L];
    constexpr int NKT = KP / 32;
    for (int idx = tid; idx < NP * KP; idx += THREADS) {
        const int f    = idx >> 9;
        const int t    = idx & 511;
        const int quad = t >> 7;
        const int colc = (t >> 3) & 15;
        const int j    = t & 7;
        const int mt   = f / NKT;
        const int kt   = f - mt * NKT;
        const int m    = mt * 16 + colc;
        const int k    = kt * 32 + quad * 8 + j;
        float v = 0.f;
        if (m < OUTl) {
            if (k < INl) v = W[m * INl + k];
            else if (k == INl) v = B[m];                    // f2bf -> bias_hi
            else if (k == INl + 1) {                        // bias_lo
                float hf = __builtin_bit_cast(float, (unsigned)f2bf(B[m]) << 16);
                v = B[m] - hf;
            }
        } else if (m == OUTl || m == OUTl + 1) {
            if (k == INl) v = 1.f;                          // 1.0-generator row
        }
        wlds[WOFF_[L] + idx] = (short)f2bf(v);
    }
}

// One Linear+ReLU layer over this wave's 16 rows, in place in `buf`.
// k-outer, all NMT accumulator chains live.
template <int L>
__device__ __forceinline__ void layer_fwd(const short* __restrict__ wlds,
                                          short* buf, int col, int quad) {
    constexpr int KP   = KP_[L];
    constexpr int NP   = NP_[L];
    constexpr int NKT  = KP / 32;
    constexpr int NMT  = NP / 16;
    constexpr int KPN  = KP_[L + 1];
    const short* wl = wlds + WOFF_[L];
    const int fo = quad * 128 + col * 8;

    f32x4 acc[NMT];
#pragma unroll
    for (int mt = 0; mt < NMT; ++mt)
        acc[mt] = f32x4{0.f, 0.f, 0.f, 0.f};

#pragma unroll
    for (int kt = 0; kt < NKT; ++kt) {
        bf16x8 b0 = *(const bf16x8*)(buf + kt * 512 + fo);
#pragma unroll
        for (int mt = 0; mt < NMT; ++mt) {
            bf16x8 af = *(const bf16x8*)(wl + (mt * NKT + kt) * 512 + fo);
            acc[mt] = __builtin_amdgcn_mfma_f32_16x16x32_bf16(af, b0, acc[mt], 0, 0, 0);
        }
    }
#pragma unroll
    for (int mt = 0; mt < NMT; ++mt) {
        const int wbase = (mt >> 1) * 512 + ((mt & 1) * 2 + (quad >> 1)) * 128 + col * 8 + (quad & 1) * 4;
        u32x2 o;
        o[0] = pk2(fmaxf(acc[mt][0], 0.f), fmaxf(acc[mt][1], 0.f));
        o[1] = pk2(fmaxf(acc[mt][2], 0.f), fmaxf(acc[mt][3], 0.f));
        *(u32x2*)(buf + wbase) = o;
    }
    // NP(16) < KPN(32): fill k in [16,32) with 0, except k==16 := 1.0
    if constexpr (NP < KPN) {
        if (quad < 2) {
            u16x8 z = {0, 0, 0, 0, 0, 0, 0, 0};
            if (quad == 0) z[0] = (unsigned short)0x3F80;
            *(u16x8*)(buf + (2 + quad) * 128 + col * 8) = z;
        }
    }
}

// Single-tile 32->16 layer (L7/L8/L9) with preloaded weight frag.
__device__ __forceinline__ void layer_one(bf16x8 af, short* buf, int col, int quad) {
    const int fo = quad * 128 + col * 8;
    bf16x8 b0 = *(const bf16x8*)(buf + fo);
    f32x4 a0 = f32x4{0.f, 0.f, 0.f, 0.f};
    a0 = __builtin_amdgcn_mfma_f32_16x16x32_bf16(af, b0, a0, 0, 0, 0);
    const int wbase = (quad >> 1) * 128 + col * 8 + (quad & 1) * 4;
    u32x2 o0;
    o0[0] = pk2(fmaxf(a0[0], 0.f), fmaxf(a0[1], 0.f));
    o0[1] = pk2(fmaxf(a0[2], 0.f), fmaxf(a0[3], 0.f));
    *(u32x2*)(buf + wbase) = o0;
    if (quad < 2) {
        u16x8 z = {0, 0, 0, 0, 0, 0, 0, 0};
        if (quad == 0) z[0] = (unsigned short)0x3F80;
        *(u16x8*)(buf + (2 + quad) * 128 + col * 8) = z;
    }
}

__device__ __forceinline__ float4 ld4(const float* p) {
    float4 t;
    __builtin_memcpy(&t, p, 16);
    return t;
}

// Fetch this wave's x row-fragment for a chunk into registers.
__device__ __forceinline__ void fetch_x(const float* __restrict__ x, int row0,
                                        int col, int quad, float4& a0) {
    const float* r0 = x + (long)(row0 + col) * 15;
    if (quad < 3) {
        a0 = ld4(r0 + quad * 4);
    } else {
        // k = 12..14 + bias-col 1.0 at k=15 (load at +11 to stay in bounds)
        float4 t0 = ld4(r0 + 11);
        a0 = make_float4(t0.y, t0.z, t0.w, 1.f);
    }
}

__device__ __forceinline__ void stage_x(short* buf, float4 a0, int col, int quad) {
    const int off = (quad >> 1) * 128 + col * 8 + (quad & 1) * 4;
    u32x2 o0;
    o0[0] = pk2(a0.x, a0.y); o0[1] = pk2(a0.z, a0.w);
    *(u32x2*)(buf + off) = o0;
    // k in [16,32): 0 except k==16 := 1.0 (bias_lo column of layer 0)
    if (quad < 2) {
        u16x8 z = {0, 0, 0, 0, 0, 0, 0, 0};
        if (quad == 0) z[0] = (unsigned short)0x3F80;
        *(u16x8*)(buf + (2 + quad) * 128 + col * 8) = z;
    }
}

extern "C" __global__ void __launch_bounds__(THREADS, 4)
mlp_fused(const float* __restrict__ x,
          const float* __restrict__ W0,  const float* __restrict__ B0,
          const float* __restrict__ W1,  const float* __restrict__ B1,
          const float* __restrict__ W2,  const float* __restrict__ B2,
          const float* __restrict__ W3,  const float* __restrict__ B3,
          const float* __restrict__ W4,  const float* __restrict__ B4,
          const float* __restrict__ W5,  const float* __restrict__ B5,
          const float* __restrict__ W6,  const float* __restrict__ B6,
          const float* __restrict__ W7,  const float* __restrict__ B7,
          const float* __restrict__ W8,  const float* __restrict__ B8,
          const float* __restrict__ W9,  const float* __restrict__ B9,
          const float* __restrict__ W10, const float* __restrict__ B10,
          float* __restrict__ out, int nchunks) {
    extern __shared__ short smem[];
    short* wlds = smem;
    short* act  = smem + ACT_OFF;

    const int tid = threadIdx.x;

    stage_w<0>(W0, B0, wlds, tid);
    stage_w<1>(W1, B1, wlds, tid);
    stage_w<2>(W2, B2, wlds, tid);
    stage_w<3>(W3, B3, wlds, tid);
    stage_w<4>(W4, B4, wlds, tid);
    stage_w<5>(W5, B5, wlds, tid);
    stage_w<6>(W6, B6, wlds, tid);
    stage_w<7>(W7, B7, wlds, tid);
    stage_w<8>(W8, B8, wlds, tid);
    stage_w<9>(W9, B9, wlds, tid);
    stage_w<10>(W10, B10, wlds, tid);
    __syncthreads();

    const int wave = tid >> 6;
    const int lane = tid & 63;
    const int col  = lane & 15;
    const int quad = lane >> 4;
    short* buf = act + wave * ARENA;
    const int fo = quad * 128 + col * 8;

    // Tail-layer weight frags live in VGPRs for the whole kernel.
    const bf16x8 w7  = *(const bf16x8*)(wlds + WOFF_[7]  + fo);
    const bf16x8 w8  = *(const bf16x8*)(wlds + WOFF_[8]  + fo);
    const bf16x8 w9  = *(const bf16x8*)(wlds + WOFF_[9]  + fo);
    const bf16x8 w10 = *(const bf16x8*)(wlds + WOFF_[10] + fo);

    int chunk = blockIdx.x;
    float4 xa;
    if (chunk < nchunks)
        fetch_x(x, chunk * ROWS_PER_BLOCK + wave * ROWS_PER_WAVE, col, quad, xa);

    for (; chunk < nchunks; chunk += gridDim.x) {
        const int row0 = chunk * ROWS_PER_BLOCK + wave * ROWS_PER_WAVE;
        stage_x(buf, xa, col, quad);

        // Prefetch next chunk's x while the layer stack runs.
        const int nxt = chunk + gridDim.x;
        if (nxt < nchunks)
            fetch_x(x, nxt * ROWS_PER_BLOCK + wave * ROWS_PER_WAVE, col, quad, xa);

        layer_fwd<0>(wlds, buf, col, quad);
        layer_fwd<1>(wlds, buf, col, quad);
        layer_fwd<2>(wlds, buf, col, quad);
        layer_fwd<3>(wlds, buf, col, quad);
        layer_fwd<4>(wlds, buf, col, quad);
        layer_fwd<5>(wlds, buf, col, quad);
        layer_fwd<6>(wlds, buf, col, quad);
        layer_one(w7, buf, col, quad);
        layer_one(w8, buf, col, quad);
        layer_one(w9, buf, col, quad);

        // Final layer (5 -> 1, bias via pads) + sigmoid.
        {
            bf16x8 b0 = *(const bf16x8*)(buf + fo);
            f32x4 a0 = f32x4{0.f, 0.f, 0.f, 0.f};
            a0 = __builtin_amdgcn_mfma_f32_16x16x32_bf16(w10, b0, a0, 0, 0, 0);
            if (quad == 0)
                out[row0 + col] = 1.f / (1.f + __expf(-a0[0]));
        }
    }
}

extern "C" void kernel_launch(void* const* d_in, const int* in_sizes, int n_in,
                              void* d_out, int out_size, void* d_ws, size_t ws_size,
                              hipStream_t stream) {
    (void)n_in; (void)d_ws; (void)ws_size; (void)out_size;
    const float* x = (const float*)d_in[0];
    const float* W[11];
    const float* B[11];
    for (int i = 0; i < 11; ++i) {
        W[i] = (const float*)d_in[1 + 2 * i];
        B[i] = (const float*)d_in[2 + 2 * i];
    }
    const int nrows   = in_sizes[0] / 15;
    const int nchunks = nrows / ROWS_PER_BLOCK;   // 524288/256 = 2048

    hipFuncSetAttribute((const void*)mlp_fused,
                        hipFuncAttributeMaxDynamicSharedMemorySize, LDS_BYTES);

    mlp_fused<<<dim3(256), dim3(THREADS), LDS_BYTES, stream>>>(
        x,
        W[0], B[0], W[1], B[1], W[2], B[2], W[3], B[3], W[4], B[4],
        W[5], B[5], W[6], B[6], W[7], B[7], W[8], B[8], W[9], B[9],
        W[10], B[10],
        (float*)d_out, nchunks);
}

// Round 2
// 177.647 us; speedup vs baseline: 1.1266x; 1.0297x over previous
//
#include <hip/hip_runtime.h>
#include <math.h>

// ---------------------------------------------------------------------------
// Fused 11-layer funnel MLP, round 5.
// Round-4 post-mortem: LDS data pipe ~92% busy (13.4 MB b128 reads/CU at
// ~85 B/cy + writes + conflicts ~= 197k of 215k cycles). Weight A-frag
// re-reads are 82 of 102 reads per wave-chunk.
// Round 5:
//  - L2's 12 weight frags (48 VGPR) preloaded to registers for the whole
//    kernel (like the tail w7-w10 already were). Peak live ~116 VGPR at
//    L3 (8 acc) -> stays under the 128 cap for 4 waves/SIMD.
//  - Pad writes shrunk: padded weight cols k in [17,32) are zero, so B
//    garbage there contributes 0; only k==16 (bias_lo col) needs 1.0.
//    Full 16B zero-fill pad writes -> single u16 write. One-time arena
//    zero at startup guards against NaN patterns in uninit LDS (NaN*0=NaN).
// Retained: fragment-major conflict-free LDS, bias folded into MFMA pad
// columns, 1.0-generator rows, v_cvt_pk_bf16_f32 epilogue, 16 waves x 16
// rows (4 waves/SIMD), x prefetch.
// ---------------------------------------------------------------------------

using bf16x8 = __attribute__((ext_vector_type(8))) short;   // 8 bf16 = 4 VGPRs
using f32x4  = __attribute__((ext_vector_type(4))) float;
using u16x8  = __attribute__((ext_vector_type(8))) unsigned short;
using u32x2  = __attribute__((ext_vector_type(2))) unsigned;
typedef __bf16 bf16x2_t __attribute__((ext_vector_type(2)));

namespace {
constexpr int NL = 11;
constexpr int IN_[NL]   = {15, 30, 60, 90, 120, 90, 60, 30, 15, 10, 5};
constexpr int OUT_[NL]  = {30, 60, 90, 120, 90, 60, 30, 15, 10, 5, 1};
constexpr int KP_[NL]   = {32, 32, 64, 96, 128, 96, 64, 32, 32, 32, 32};  // in, pad 32
constexpr int NP_[NL]   = {32, 64, 96, 128, 96, 64, 32, 16, 16, 16, 16};  // out, pad 16
constexpr int WOFF_[NL] = {0, 1024, 3072, 9216, 21504, 33792, 39936, 41984, 42496, 43008, 43520};
constexpr int WTOT      = 44032;   // shorts
constexpr int ACT_OFF   = WTOT;
constexpr int WAVES     = 16;
constexpr int THREADS   = WAVES * 64;                 // 1024
constexpr int ROWS_PER_WAVE  = 16;
constexpr int ROWS_PER_BLOCK = WAVES * ROWS_PER_WAVE; // 256
constexpr int ARENA     = 2048;    // shorts per wave (4 KB)
constexpr int LDS_BYTES = (WTOT + WAVES * ARENA) * 2; // 153600
}

// fp32 -> bf16 RNE (scalar, staging only)
__device__ __forceinline__ unsigned short f2bf(float f) {
    unsigned u = __float_as_uint(f);
    u += 0x7fffu + ((u >> 16) & 1u);
    return (unsigned short)(u >> 16);
}

// packed fp32x2 -> bf16x2 (RNE); gfx950 has v_cvt_pk_bf16_f32
__device__ __forceinline__ unsigned pk2(float a, float b) {
#if __has_builtin(__builtin_amdgcn_cvt_pk_bf16_f32)
    return __builtin_bit_cast(unsigned, __builtin_amdgcn_cvt_pk_bf16_f32(a, b));
#else
    bf16x2_t c;
    c[0] = (__bf16)a;
    c[1] = (__bf16)b;
    return __builtin_bit_cast(unsigned, c);
#endif
}

// Stage layer L's weights (A-frag-major) with bias/one-hot pads folded in.
template <int L>
__device__ __forceinline__ void stage_w(const float* __restrict__ W,
                                        const float* __restrict__ B,
                                        short* wlds, int tid) {
    constexpr int KP = KP_[L], NP = NP_[L], INl = IN_[L], OUTl = OUT_[L];
    constexpr int NKT = KP / 32;
    for (int idx = tid; idx < NP * KP; idx += THREADS) {
        const int f    = idx >> 9;
        const int t    = idx & 511;
        const int quad = t >> 7;
        const int colc = (t >> 3) & 15;
        const int j    = t & 7;
        const int mt   = f / NKT;
        const int kt   = f - mt * NKT;
        const int m    = mt * 16 + colc;
        const int k    = kt * 32 + quad * 8 + j;
        float v = 0.f;
        if (m < OUTl) {
            if (k < INl) v = W[m * INl + k];
            else if (k == INl) v = B[m];                    // f2bf -> bias_hi
            else if (k == INl + 1) {                        // bias_lo
                float hf = __builtin_bit_cast(float, (unsigned)f2bf(B[m]) << 16);
                v = B[m] - hf;
            }
        } else if (m == OUTl || m == OUTl + 1) {
            if (k == INl) v = 1.f;                          // 1.0-generator row
        }
        wlds[WOFF_[L] + idx] = (short)f2bf(v);
    }
}

// One Linear+ReLU layer over this wave's 16 rows, in place in `buf`.
// k-outer, all NMT accumulator chains live. Weights read from LDS.
template <int L>
__device__ __forceinline__ void layer_fwd(const short* __restrict__ wlds,
                                          short* buf, int col, int quad) {
    constexpr int KP   = KP_[L];
    constexpr int NP   = NP_[L];
    constexpr int NKT  = KP / 32;
    constexpr int NMT  = NP / 16;
    const short* wl = wlds + WOFF_[L];
    const int fo = quad * 128 + col * 8;

    f32x4 acc[NMT];
#pragma unroll
    for (int mt = 0; mt < NMT; ++mt)
        acc[mt] = f32x4{0.f, 0.f, 0.f, 0.f};

#pragma unroll
    for (int kt = 0; kt < NKT; ++kt) {
        bf16x8 b0 = *(const bf16x8*)(buf + kt * 512 + fo);
#pragma unroll
        for (int mt = 0; mt < NMT; ++mt) {
            bf16x8 af = *(const bf16x8*)(wl + (mt * NKT + kt) * 512 + fo);
            acc[mt] = __builtin_amdgcn_mfma_f32_16x16x32_bf16(af, b0, acc[mt], 0, 0, 0);
        }
    }
#pragma unroll
    for (int mt = 0; mt < NMT; ++mt) {
        const int wbase = (mt >> 1) * 512 + ((mt & 1) * 2 + (quad >> 1)) * 128 + col * 8 + (quad & 1) * 4;
        u32x2 o;
        o[0] = pk2(fmaxf(acc[mt][0], 0.f), fmaxf(acc[mt][1], 0.f));
        o[1] = pk2(fmaxf(acc[mt][2], 0.f), fmaxf(acc[mt][3], 0.f));
        *(u32x2*)(buf + wbase) = o;
    }
    // NP == KP_[L+1] for all layers using this path: no pad writes needed.
}

// Same layer body, but with the weight fragments preloaded in VGPRs.
template <int L, int NF>
__device__ __forceinline__ void layer_fwd_pre(const bf16x8 (&wf)[NF],
                                              short* buf, int col, int quad) {
    constexpr int KP  = KP_[L];
    constexpr int NP  = NP_[L];
    constexpr int NKT = KP / 32;
    constexpr int NMT = NP / 16;
    static_assert(NF == NKT * NMT, "frag count mismatch");
    const int fo = quad * 128 + col * 8;

    f32x4 acc[NMT];
#pragma unroll
    for (int mt = 0; mt < NMT; ++mt)
        acc[mt] = f32x4{0.f, 0.f, 0.f, 0.f};

#pragma unroll
    for (int kt = 0; kt < NKT; ++kt) {
        bf16x8 b0 = *(const bf16x8*)(buf + kt * 512 + fo);
#pragma unroll
        for (int mt = 0; mt < NMT; ++mt)
            acc[mt] = __builtin_amdgcn_mfma_f32_16x16x32_bf16(wf[mt * NKT + kt], b0, acc[mt], 0, 0, 0);
    }
#pragma unroll
    for (int mt = 0; mt < NMT; ++mt) {
        const int wbase = (mt >> 1) * 512 + ((mt & 1) * 2 + (quad >> 1)) * 128 + col * 8 + (quad & 1) * 4;
        u32x2 o;
        o[0] = pk2(fmaxf(acc[mt][0], 0.f), fmaxf(acc[mt][1], 0.f));
        o[1] = pk2(fmaxf(acc[mt][2], 0.f), fmaxf(acc[mt][3], 0.f));
        *(u32x2*)(buf + wbase) = o;
    }
}

// Single-tile 32->16 layer (L7/L8/L9) with preloaded weight frag.
// Pad: only k==16 (bias_lo col) needs 1.0 -- padded weight cols k in
// [17,32) are zero, so leftover finite bf16 there contributes 0.
__device__ __forceinline__ void layer_one(bf16x8 af, short* buf, int col, int quad) {
    const int fo = quad * 128 + col * 8;
    bf16x8 b0 = *(const bf16x8*)(buf + fo);
    f32x4 a0 = f32x4{0.f, 0.f, 0.f, 0.f};
    a0 = __builtin_amdgcn_mfma_f32_16x16x32_bf16(af, b0, a0, 0, 0, 0);
    const int wbase = (quad >> 1) * 128 + col * 8 + (quad & 1) * 4;
    u32x2 o0;
    o0[0] = pk2(fmaxf(a0[0], 0.f), fmaxf(a0[1], 0.f));
    o0[1] = pk2(fmaxf(a0[2], 0.f), fmaxf(a0[3], 0.f));
    *(u32x2*)(buf + wbase) = o0;
    if (quad == 0) buf[256 + col * 8] = (short)0x3F80;   // k==16 := 1.0
}

__device__ __forceinline__ float4 ld4(const float* p) {
    float4 t;
    __builtin_memcpy(&t, p, 16);
    return t;
}

// Fetch this wave's x row-fragment for a chunk into registers.
__device__ __forceinline__ void fetch_x(const float* __restrict__ x, int row0,
                                        int col, int quad, float4& a0) {
    const float* r0 = x + (long)(row0 + col) * 15;
    if (quad < 3) {
        a0 = ld4(r0 + quad * 4);
    } else {
        // k = 12..14 + bias-col 1.0 at k=15 (load at +11 to stay in bounds)
        float4 t0 = ld4(r0 + 11);
        a0 = make_float4(t0.y, t0.z, t0.w, 1.f);
    }
}

__device__ __forceinline__ void stage_x(short* buf, float4 a0, int col, int quad) {
    const int off = (quad >> 1) * 128 + col * 8 + (quad & 1) * 4;
    u32x2 o0;
    o0[0] = pk2(a0.x, a0.y); o0[1] = pk2(a0.z, a0.w);
    *(u32x2*)(buf + off) = o0;
    // bias_lo column of layer 0: k==16 := 1.0; k in [17,32) are don't-care
    // (weight cols zero) and stay finite from prior writes / startup zero.
    if (quad == 0) buf[256 + col * 8] = (short)0x3F80;
}

extern "C" __global__ void __launch_bounds__(THREADS, 4)
mlp_fused(const float* __restrict__ x,
          const float* __restrict__ W0,  const float* __restrict__ B0,
          const float* __restrict__ W1,  const float* __restrict__ B1,
          const float* __restrict__ W2,  const float* __restrict__ B2,
          const float* __restrict__ W3,  const float* __restrict__ B3,
          const float* __restrict__ W4,  const float* __restrict__ B4,
          const float* __restrict__ W5,  const float* __restrict__ B5,
          const float* __restrict__ W6,  const float* __restrict__ B6,
          const float* __restrict__ W7,  const float* __restrict__ B7,
          const float* __restrict__ W8,  const float* __restrict__ B8,
          const float* __restrict__ W9,  const float* __restrict__ B9,
          const float* __restrict__ W10, const float* __restrict__ B10,
          float* __restrict__ out, int nchunks) {
    extern __shared__ short smem[];
    short* wlds = smem;
    short* act  = smem + ACT_OFF;

    const int tid = threadIdx.x;

    stage_w<0>(W0, B0, wlds, tid);
    stage_w<1>(W1, B1, wlds, tid);
    stage_w<2>(W2, B2, wlds, tid);
    stage_w<3>(W3, B3, wlds, tid);
    stage_w<4>(W4, B4, wlds, tid);
    stage_w<5>(W5, B5, wlds, tid);
    stage_w<6>(W6, B6, wlds, tid);
    stage_w<7>(W7, B7, wlds, tid);
    stage_w<8>(W8, B8, wlds, tid);
    stage_w<9>(W9, B9, wlds, tid);
    stage_w<10>(W10, B10, wlds, tid);
    __syncthreads();

    const int wave = tid >> 6;
    const int lane = tid & 63;
    const int col  = lane & 15;
    const int quad = lane >> 4;
    short* buf = act + wave * ARENA;
    const int fo = quad * 128 + col * 8;

    // One-time arena zero: guards the don't-care B regions against NaN
    // patterns in uninitialized LDS (NaN * 0-weight = NaN in MFMA).
    {
        u16x8 z = {0, 0, 0, 0, 0, 0, 0, 0};
#pragma unroll
        for (int i = 0; i < 4; ++i)
            *(u16x8*)(buf + (lane + i * 64) * 8) = z;
    }

    // Tail-layer weight frags live in VGPRs for the whole kernel.
    const bf16x8 w7  = *(const bf16x8*)(wlds + WOFF_[7]  + fo);
    const bf16x8 w8  = *(const bf16x8*)(wlds + WOFF_[8]  + fo);
    const bf16x8 w9  = *(const bf16x8*)(wlds + WOFF_[9]  + fo);
    const bf16x8 w10 = *(const bf16x8*)(wlds + WOFF_[10] + fo);

    // L2's 12 weight frags (48 VGPR) preloaded for the whole kernel:
    // cuts 12 of the 82 per-chunk weight LDS reads per wave.
    bf16x8 wf2[12];
#pragma unroll
    for (int i = 0; i < 12; ++i)
        wf2[i] = *(const bf16x8*)(wlds + WOFF_[2] + i * 512 + fo);

    int chunk = blockIdx.x;
    float4 xa;
    if (chunk < nchunks)
        fetch_x(x, chunk * ROWS_PER_BLOCK + wave * ROWS_PER_WAVE, col, quad, xa);

    for (; chunk < nchunks; chunk += gridDim.x) {
        const int row0 = chunk * ROWS_PER_BLOCK + wave * ROWS_PER_WAVE;
        stage_x(buf, xa, col, quad);

        // Prefetch next chunk's x while the layer stack runs.
        const int nxt = chunk + gridDim.x;
        if (nxt < nchunks)
            fetch_x(x, nxt * ROWS_PER_BLOCK + wave * ROWS_PER_WAVE, col, quad, xa);

        layer_fwd<0>(wlds, buf, col, quad);
        layer_fwd<1>(wlds, buf, col, quad);
        layer_fwd_pre<2, 12>(wf2, buf, col, quad);
        layer_fwd<3>(wlds, buf, col, quad);
        layer_fwd<4>(wlds, buf, col, quad);
        layer_fwd<5>(wlds, buf, col, quad);
        layer_fwd<6>(wlds, buf, col, quad);
        layer_one(w7, buf, col, quad);
        layer_one(w8, buf, col, quad);
        layer_one(w9, buf, col, quad);

        // Final layer (5 -> 1, bias via pads) + sigmoid.
        {
            bf16x8 b0 = *(const bf16x8*)(buf + fo);
            f32x4 a0 = f32x4{0.f, 0.f, 0.f, 0.f};
            a0 = __builtin_amdgcn_mfma_f32_16x16x32_bf16(w10, b0, a0, 0, 0, 0);
            if (quad == 0)
                out[row0 + col] = 1.f / (1.f + __expf(-a0[0]));
        }
    }
}

extern "C" void kernel_launch(void* const* d_in, const int* in_sizes, int n_in,
                              void* d_out, int out_size, void* d_ws, size_t ws_size,
                              hipStream_t stream) {
    (void)n_in; (void)d_ws; (void)ws_size; (void)out_size;
    const float* x = (const float*)d_in[0];
    const float* W[11];
    const float* B[11];
    for (int i = 0; i < 11; ++i) {
        W[i] = (const float*)d_in[1 + 2 * i];
        B[i] = (const float*)d_in[2 + 2 * i];
    }
    const int nrows   = in_sizes[0] / 15;
    const int nchunks = nrows / ROWS_PER_BLOCK;   // 524288/256 = 2048

    hipFuncSetAttribute((const void*)mlp_fused,
                        hipFuncAttributeMaxDynamicSharedMemorySize, LDS_BYTES);

    mlp_fused<<<dim3(256), dim3(THREADS), LDS_BYTES, stream>>>(
        x,
        W[0], B[0], W[1], B[1], W[2], B[2], W[3], B[3], W[4], B[4],
        W[5], B[5], W[6], B[6], W[7], B[7], W[8], B[8], W[9], B[9],
        W[10], B[10],
        (float*)d_out, nchunks);
}